// Round 10
// baseline (233.629 us; speedup 1.0000x reference)
//
#include <hip/hip_runtime.h>
#include <math.h>

#define L 8
#define N 32768
#define H 404
#define D 128
#define F 532
#define NT 17             // K-tiles of 32 (17*32=544 >= F; tile beyond is all-zero B)
#define GRU_BLOCKS 101    // one wave per hidden index

typedef __attribute__((ext_vector_type(8))) _Float16 half8;
typedef __attribute__((ext_vector_type(4))) float f32x4;
typedef __attribute__((address_space(3))) unsigned int as3_u32;
typedef __attribute__((address_space(1))) unsigned int as1_u32;

// workspace layout (float offsets)
#define WS_WH2     0                        // 17*4*128*8 fp16 = 34816 floats (tiled B)
#define WS_HMAXK   (WS_WH2 + 36864)         // 8*128 uint keys
#define WS_HSEL    (WS_HMAXK + L * D)       // 7*128
#define WS_GI      (WS_HSEL + (L - 1) * D)  // 8*1212
#define WS_HBUF    (WS_GI + L * 3 * H)      // 2*404
#define WS_V       (WS_HBUF + 2 * H)        // 532
#define WS_HS      (WS_V + F)               // 128
#define WS_SCAL    (WS_HS + D)              // c, M, S, spare
#define WS_CNT     (WS_SCAL + 4)            // gru barrier counter
#define WS_LOGITS  (WS_CNT + 4)             // 32769

__device__ __forceinline__ unsigned encf(float f) {
    unsigned u = __float_as_uint(f);
    return (u & 0x80000000u) ? ~u : (u | 0x80000000u);
}
__device__ __forceinline__ float decf(unsigned u) {
    unsigned b = (u & 0x80000000u) ? (u ^ 0x80000000u) : ~u;
    return __uint_as_float(b);
}
__device__ __forceinline__ float sigmoidf_(float x) {
    return 1.0f / (1.0f + __expf(-x));
}
__device__ __forceinline__ unsigned pk_f16(float a, float b) {
    auto h = __builtin_amdgcn_cvt_pkrtz(a, b);
    return *(unsigned*)&h;
}
__device__ __forceinline__ half8 pack8(float4 x0, float4 x1) {
    uint4 u = { pk_f16(x0.x, x0.y), pk_f16(x0.z, x0.w),
                pk_f16(x1.x, x1.y), pk_f16(x1.z, x1.w) };
    return *(half8*)&u;
}
__device__ __forceinline__ void gld16(const void* g, void* l) {
    __builtin_amdgcn_global_load_lds((const as1_u32*)g, (as3_u32*)l, 16, 0, 0);
}

// ---- prep: B tiles wh2[tile][kg][col][8] fp16 (k = tile*32+kg*8+e, zero past F) ----
__global__ void k_prep(const float* __restrict__ Wfa, unsigned short* __restrict__ wh2,
                       unsigned* __restrict__ keys, unsigned* __restrict__ cnt) {
    int i = blockIdx.x * 256 + threadIdx.x;
    if (i < L * D) keys[i] = 0u;           // decodes below all finite values
    if (i == 2000) *cnt = 0u;
    if (i >= NT * 4 * 128) return;
    int tile = i >> 9;
    int rem = i & 511;
    int kg = rem >> 7, c = rem & 127;
    int k0 = tile * 32 + kg * 8;
    unsigned short v[8];
#pragma unroll
    for (int e = 0; e < 8; ++e) {
        int k = k0 + e;
        float x = (k < F) ? Wfa[c * F + k] : 0.0f;
        _Float16 h = (_Float16)x;
        v[e] = *(unsigned short*)&h;
    }
    *(uint4*)(wh2 + (long)i * 8) = *(uint4*)v;
}

// ---- big einsum: double-buffered async staging, counted vmcnt (T3/T4) ----
// grid 2048: l = bid>>8, 128-row chunk = bid&255. 4 waves, each 64x64 output.
// LDS per buf: A fp32 [128 rows][8 chunks16B, XOR row&7] 16 KB + B fp16 [kg][col] 8 KB.
__global__ __launch_bounds__(256, 3)
void k_big(const float* __restrict__ nb, const unsigned short* __restrict__ wh2,
           const float* __restrict__ bfa, const int* __restrict__ aid,
           unsigned* __restrict__ hmaxk, float* __restrict__ hsel) {
    __shared__ float As[2][128 * 32];            // 2 x 16 KB
    __shared__ unsigned short Bs[2][128 * 32];   // 2 x 8 KB

    const int bid = blockIdx.x;
    const int l_hop = bid >> 8;
    const int row0 = (bid & 255) * 128;
    const int tid = threadIdx.x;
    const int lane = tid & 63, w = tid >> 6;
    const int wm = w >> 1, wn = w & 1;
    const int lr = lane & 15, kg = lane >> 4;

    const float* xbase = nb + ((long)l_hop * N + row0) * F;

    f32x4 acc[4][4];
    float bv[4];
#pragma unroll
    for (int n = 0; n < 4; ++n) bv[n] = bfa[wn * 64 + n * 16 + lr];
#pragma unroll
    for (int m = 0; m < 4; ++m)
#pragma unroll
        for (int n = 0; n < 4; ++n) {
            acc[m][n][0] = bv[n]; acc[m][n][1] = bv[n];
            acc[m][n][2] = bv[n]; acc[m][n][3] = bv[n];
        }

    const int srw = lane >> 3;         // A-stage: row within 8-row group
    const int sch = lane & 7;          // A-stage: dest chunk

    // stage tile kt into buffer buf: 6 async issues per thread (4 A + 2 B)
    auto STAGE = [&](int kt, int buf) {
        const int fc = kt * 32;
#pragma unroll
        for (int it = 0; it < 4; ++it) {
            int rbase = it * 32 + w * 8;           // multiple of 8
            int row = rbase + srw;
            int cg = sch ^ srw;                    // row&7 == srw
            int col0 = fc + cg * 4;
            const float* src = xbase + (long)row * F + ((col0 < F) ? col0 : 0);
            gld16(src, (char*)As[buf] + rbase * 128);
        }
#pragma unroll
        for (int it = 0; it < 2; ++it) {
            int off = it * 4096 + w * 1024;
            gld16((const char*)wh2 + (long)kt * 8192 + off + lane * 16,
                  (char*)Bs[buf] + off);
        }
    };

    // consume one tile: 16 MFMA per wave
    auto CMP = [&](int buf) {
        const char* Ab = (const char*)As[buf];
        const char* Bb = (const char*)Bs[buf];
        half8 b[4];
#pragma unroll
        for (int n = 0; n < 4; ++n)
            b[n] = *(const half8*)(Bb + kg * 2048 + (wn * 64 + n * 16 + lr) * 16);
#pragma unroll
        for (int m = 0; m < 4; ++m) {
            int row = wm * 64 + m * 16 + lr;
            const char* base = Ab + row * 128;
            int c0 = kg * 2;
            float4 x0 = *(const float4*)(base + ((c0 ^ (row & 7)) << 4));
            float4 x1 = *(const float4*)(base + (((c0 + 1) ^ (row & 7)) << 4));
            half8 a = pack8(x0, x1);
#pragma unroll
            for (int n = 0; n < 4; ++n)
                acc[m][n] = __builtin_amdgcn_mfma_f32_16x16x32_f16(a, b[n], acc[m][n], 0, 0, 0);
        }
    };

    // prologue: fill both buffers
    STAGE(0, 0);
    STAGE(1, 1);

    for (int kt = 0; kt < NT - 1; ++kt) {
        // wait for tile kt's 6 loads (tile kt+1's 6 stay in flight)
        asm volatile("s_waitcnt vmcnt(6)" ::: "memory");
        __builtin_amdgcn_s_barrier();
        __builtin_amdgcn_sched_barrier(0);
        CMP(kt & 1);
        __builtin_amdgcn_s_barrier();          // all waves done reading buf kt&1
        __builtin_amdgcn_sched_barrier(0);
        if (kt + 2 < NT) STAGE(kt + 2, kt & 1);
    }
    // epilogue: last tile
    asm volatile("s_waitcnt vmcnt(0)" ::: "memory");
    __builtin_amdgcn_s_barrier();
    __builtin_amdgcn_sched_barrier(0);
    CMP((NT - 1) & 1);

    __syncthreads();   // LDS reads done; reuse As for cross-wave max

    // selected-action row (compile-time acc indexing)
    if (l_hop < L - 1) {
        int br = aid[l_hop] - row0;
        if (br >= 0 && br < 128 && (br >> 6) == wm && ((br >> 2) & 3) == kg) {
            int msel = (br >> 4) & 3, rsel = br & 3;
#pragma unroll
            for (int n = 0; n < 4; ++n) {
                float vsel = 0.f;
#pragma unroll
                for (int m = 0; m < 4; ++m)
#pragma unroll
                    for (int r = 0; r < 4; ++r)
                        if (m == msel && r == rsel) vsel = acc[m][n][r];
                hsel[l_hop * D + wn * 64 + n * 16 + lr] = vsel;
            }
        }
    }

    // column max: thread-local -> cross-lane-group shfl -> cross-wave LDS -> atomic
    float cmax[4];
#pragma unroll
    for (int n = 0; n < 4; ++n) {
        float m0 = acc[0][n][0];
#pragma unroll
        for (int m = 0; m < 4; ++m)
#pragma unroll
            for (int r = 0; r < 4; ++r) m0 = fmaxf(m0, acc[m][n][r]);
        m0 = fmaxf(m0, __shfl_xor(m0, 16, 64));
        m0 = fmaxf(m0, __shfl_xor(m0, 32, 64));
        cmax[n] = m0;
    }
    float* wmaxp = (float*)As;   // [2][128]
    if (kg == 0) {
#pragma unroll
        for (int n = 0; n < 4; ++n)
            wmaxp[wm * 128 + wn * 64 + n * 16 + lr] = cmax[n];
    }
    __syncthreads();
    if (tid < 128) {
        float mval = fmaxf(wmaxp[tid], wmaxp[128 + tid]);
        atomicMax(&hmaxk[l_hop * D + tid], encf(mval));
    }
}

// ---- gi for all 8 GRU steps: one wave per output row, coalesced W_ih reads ----
__global__ void k_gi(const float* __restrict__ Wih, const float* __restrict__ bih,
                     const float* __restrict__ pn, const unsigned* __restrict__ hmaxk,
                     const float* __restrict__ hsel, float* __restrict__ gi) {
    __shared__ float xs[L][3 * D];
    const int tid = threadIdx.x;
    for (int i = tid; i < L * 3 * D; i += 256) {
        int t = i / (3 * D), k = i % (3 * D);
        float x;
        if (t == 0) {
            x = (k < 2 * D) ? 0.0f : pn[k - 2 * D];
        } else {
            if (k < D)            x = decf(hmaxk[(t - 1) * D + k]);
            else if (k < 2 * D)   x = hsel[(t - 1) * D + (k - D)];
            else                  x = pn[t * D + (k - 2 * D)];
        }
        xs[t][k] = x;
    }
    __syncthreads();

    const int lane = tid & 63;
    const int row = blockIdx.x * 4 + (tid >> 6);   // 0..1211
    const float* wr = Wih + (long)row * 3 * D;
    float s[L];
#pragma unroll
    for (int t = 0; t < L; ++t) s[t] = 0.f;
#pragma unroll
    for (int c = 0; c < 6; ++c) {
        int k = lane + c * 64;
        float wv = wr[k];
#pragma unroll
        for (int t = 0; t < L; ++t) s[t] = fmaf(wv, xs[t][k], s[t]);
    }
#pragma unroll
    for (int t = 0; t < L; ++t)
        for (int off = 1; off < 64; off <<= 1) s[t] += __shfl_xor(s[t], off, 64);
    if (lane == 0) {
        float b = bih[row];
#pragma unroll
        for (int t = 0; t < L; ++t) gi[t * 3 * H + row] = s[t] + b;
    }
}

// ---- all 8 GRU steps in ONE kernel; one wave per hidden j; grid barrier ----
__global__ __launch_bounds__(256, 1)
void k_gru(const float* __restrict__ Whh, const float* __restrict__ bhh,
           const float* __restrict__ gi, const float* __restrict__ query,
           float* __restrict__ hbuf, unsigned* __restrict__ cnt) {
    const int tid = threadIdx.x;
    const int lane = tid & 63;
    const int j = blockIdx.x * 4 + (tid >> 6);     // 0..403

    float wr[7], wz[7], wnn[7];
#pragma unroll
    for (int c = 0; c < 7; ++c) {
        int i = lane + c * 64;
        bool ok = i < H;
        wr[c]  = ok ? Whh[(long)j * H + i]           : 0.f;
        wz[c]  = ok ? Whh[(long)(H + j) * H + i]     : 0.f;
        wnn[c] = ok ? Whh[(long)(2 * H + j) * H + i] : 0.f;
    }
    float b_r = 0.f, b_z = 0.f, b_n = 0.f;
    if (lane == 0) { b_r = bhh[j]; b_z = bhh[H + j]; b_n = bhh[2 * H + j]; }

    for (int t = 0; t < L; ++t) {
        const float* hin = (t == 0) ? query : (hbuf + ((t - 1) & 1) * H);
        float* hout = hbuf + (t & 1) * H;
        float pr = 0.f, pz = 0.f, pn2 = 0.f;
#pragma unroll
        for (int c = 0; c < 7; ++c) {
            int i = lane + c * 64;
            float hv = 0.f;
            if (i < H)
                hv = (t == 0) ? hin[i]
                              : __hip_atomic_load(hin + i, __ATOMIC_RELAXED,
                                                  __HIP_MEMORY_SCOPE_AGENT);
            pr  = fmaf(wr[c],  hv, pr);
            pz  = fmaf(wz[c],  hv, pz);
            pn2 = fmaf(wnn[c], hv, pn2);
        }
        for (int off = 1; off < 64; off <<= 1) {
            pr  += __shfl_xor(pr, off, 64);
            pz  += __shfl_xor(pz, off, 64);
            pn2 += __shfl_xor(pn2, off, 64);
        }
        if (lane == 0) {
            const float* gt = gi + t * 3 * H;
            float hprev = (t == 0) ? hin[j]
                                   : __hip_atomic_load(hin + j, __ATOMIC_RELAXED,
                                                       __HIP_MEMORY_SCOPE_AGENT);
            float r  = sigmoidf_(gt[j] + pr + b_r);
            float z  = sigmoidf_(gt[H + j] + pz + b_z);
            float nn = tanhf(gt[2 * H + j] + r * (pn2 + b_n));
            float hv = (1.0f - z) * nn + z * hprev;
            __hip_atomic_store(hout + j, hv, __ATOMIC_RELAXED,
                               __HIP_MEMORY_SCOPE_AGENT);
        }
        if (t < L - 1) {
            __syncthreads();
            if (tid == 0) {
                __hip_atomic_fetch_add(cnt, 1u, __ATOMIC_RELEASE,
                                       __HIP_MEMORY_SCOPE_AGENT);
                unsigned target = (unsigned)GRU_BLOCKS * (t + 1);
                while (__hip_atomic_load(cnt, __ATOMIC_ACQUIRE,
                                         __HIP_MEMORY_SCOPE_AGENT) < target)
                    __builtin_amdgcn_s_sleep(2);
            }
            __syncthreads();
        }
    }
}

// ---- hSt + v + u0 + c in one block (1024 thr, 16 waves) ----
__global__ void k_final(const float* __restrict__ qt, const float* __restrict__ Wfs,
                        const float* __restrict__ bfs, const float* __restrict__ Wfp,
                        const float* __restrict__ bfp, const float* __restrict__ bfa,
                        const float* __restrict__ Wfa, const unsigned* __restrict__ hmaxk,
                        float* __restrict__ v, float* __restrict__ scal,
                        float* __restrict__ logits) {
    __shared__ float hs[D];
    int tid = threadIdx.x, lane = tid & 63, wid = tid >> 6;
#pragma unroll
    for (int dd = 0; dd < 8; ++dd) {
        int d = wid * 8 + dd;
        float s = 0.f;
#pragma unroll
        for (int c = 0; c < 7; ++c) {
            int i = lane + c * 64;
            if (i < H) s = fmaf(qt[i], Wfs[(long)d * H + i], s);
        }
        for (int off = 1; off < 64; off <<= 1) s += __shfl_xor(s, off, 64);
        if (lane == 0) hs[d] = s + bfs[d];
    }
    __syncthreads();
    if (tid < F) {
        float s = 0.f;
#pragma unroll 16
        for (int d = 0; d < D; ++d) s = fmaf(hs[d], Wfa[(long)d * F + tid], s);
        v[tid] = s;
    } else if (tid == F) {
        float s = bfp[0];
        for (int d = 0; d < D; ++d) {
            s = fmaf(hs[d], Wfp[d], s);
            s = fmaf(decf(hmaxk[(L - 1) * D + d]), Wfp[D + d], s);
        }
        logits[0] = s;
    } else if (tid == F + 1) {
        float c2 = 0.f;
        for (int d = 0; d < D; ++d) c2 = fmaf(hs[d], bfa[d], c2);
        scal[0] = c2;
    }
}

// ---- uks logits (exact fp32 path); one wave per neighbor row of hop 7 ----
__global__ void k_uks(const float* __restrict__ nb7, const float* __restrict__ v,
                      const float* __restrict__ scal, float* __restrict__ logits) {
    long n = (long)blockIdx.x * 4 + (threadIdx.x >> 6);
    int lane = threadIdx.x & 63;
    const float* row = nb7 + n * F;
    float s = 0.f;
    for (int f = lane; f < F; f += 64) s = fmaf(v[f], row[f], s);
    for (int off = 1; off < 64; off <<= 1) s += __shfl_xor(s, off, 64);
    if (lane == 0) logits[1 + n] = s + scal[0];
}

// ---- softmax reduce over 32769 (single block, 1024 thr) ----
__global__ void k_sm12(const float* __restrict__ logits, float* __restrict__ scal) {
    __shared__ float sm[16], ss[16];
    int tid = threadIdx.x, lane = tid & 63, wid = tid >> 6;
    float m = -3.4e38f, s = 0.f;
    for (int i = tid; i <= N; i += 1024) {
        float x = logits[i];
        if (x > m) { s = s * __expf(m - x) + 1.0f; m = x; }
        else       { s += __expf(x - m); }
    }
    for (int off = 1; off < 64; off <<= 1) {
        float m2 = __shfl_xor(m, off, 64);
        float s2 = __shfl_xor(s, off, 64);
        float M = fmaxf(m, m2);
        s = s * __expf(m - M) + s2 * __expf(m2 - M);
        m = M;
    }
    if (lane == 0) { sm[wid] = m; ss[wid] = s; }
    __syncthreads();
    if (tid == 0) {
        float M = sm[0], S = 0.f;
        for (int k = 1; k < 16; ++k) M = fmaxf(M, sm[k]);
        for (int k = 0; k < 16; ++k) S += ss[k] * __expf(sm[k] - M);
        scal[1] = M; scal[2] = S;
    }
}

__global__ void k_sm3(const float* __restrict__ logits, const float* __restrict__ scal,
                      float* __restrict__ out) {
    int i = blockIdx.x * 256 + threadIdx.x;
    if (i <= N) out[i] = __expf(logits[i] - scal[1]) / scal[2];
}

extern "C" void kernel_launch(void* const* d_in, const int* in_sizes, int n_in,
                              void* d_out, int out_size, void* d_ws, size_t ws_size,
                              hipStream_t stream) {
    const float* query = (const float*)d_in[0];
    const float* pn    = (const float*)d_in[1];
    const float* nb    = (const float*)d_in[2];
    const int*   aid   = (const int*)d_in[3];
    const float* Wih   = (const float*)d_in[4];
    const float* Whh   = (const float*)d_in[5];
    const float* bih   = (const float*)d_in[6];
    const float* bhh   = (const float*)d_in[7];
    const float* Wfa   = (const float*)d_in[8];
    const float* bfa   = (const float*)d_in[9];
    const float* Wfs   = (const float*)d_in[10];
    const float* bfs   = (const float*)d_in[11];
    const float* Wfp   = (const float*)d_in[12];
    const float* bfp   = (const float*)d_in[13];

    float* ws = (float*)d_ws;
    unsigned short* wh2   = (unsigned short*)(ws + WS_WH2);
    unsigned*       hmaxk = (unsigned*)(ws + WS_HMAXK);
    unsigned*       cnt   = (unsigned*)(ws + WS_CNT);
    float* hsel   = ws + WS_HSEL;
    float* gi     = ws + WS_GI;
    float* hbuf   = ws + WS_HBUF;
    float* v      = ws + WS_V;
    float* scal   = ws + WS_SCAL;
    float* logits = ws + WS_LOGITS;
    float* out    = (float*)d_out;

    k_prep<<<(NT * 4 * 128 + 255) / 256, 256, 0, stream>>>(Wfa, wh2, hmaxk, cnt);
    k_big <<<L * 256, 256, 0, stream>>>(nb, wh2, bfa, aid, hmaxk, hsel);
    k_gi  <<<303, 256, 0, stream>>>(Wih, bih, pn, hmaxk, hsel, gi);
    k_gru <<<GRU_BLOCKS, 256, 0, stream>>>(Whh, bhh, gi, query, hbuf, cnt);

    const float* qt = hbuf + ((L - 1) & 1) * H;   // hbuf[1]
    k_final<<<1, 1024, 0, stream>>>(qt, Wfs, bfs, Wfp, bfp, bfa, Wfa, hmaxk, v, scal, logits);
    k_uks  <<<N / 4, 256, 0, stream>>>(nb + (long)(L - 1) * N * F, v, scal, logits);

    k_sm12<<<1, 1024, 0, stream>>>(logits, scal);
    k_sm3 <<<(N + 1 + 255) / 256, 256, 0, stream>>>(logits, scal, out);
}